// Round 1
// baseline (506.064 us; speedup 1.0000x reference)
//
#include <hip/hip_runtime.h>
#include <hip/hip_bf16.h>
#include <stdint.h>

// Problem: B=8, S=2048, F=1024 single-head causal self-attention.
// q = x@Wq^T+bq ; k,v likewise ; scores = (q k^T)/32, pad+causal mask, softmax ; out = P v
// Strategy: bf16 MFMA GEMMs (threshold 8.2e-2 permits bf16), causal tile skipping.

#define S_LEN 2048
#define F_DIM 1024
#define NBATCH 8
#define BS_TOT (NBATCH * S_LEN)   // 16384 rows

typedef __attribute__((ext_vector_type(8))) short bf16x8;
typedef __attribute__((ext_vector_type(4))) float f32x4;
typedef unsigned short u16;

__device__ __forceinline__ u16 f32_to_bf16_rne(float f) {
    union { float f; uint32_t u; } v; v.f = f;
    uint32_t u = v.u;
    u += 0x7FFFu + ((u >> 16) & 1u);
    return (u16)(u >> 16);
}

// ---------------- fp32 -> bf16 convert (vectorized) ----------------
__global__ __launch_bounds__(256) void cvt_f32_bf16(const float* __restrict__ in,
                                                    u16* __restrict__ out, int n) {
    int i = (blockIdx.x * 256 + threadIdx.x) * 4;
    if (i + 3 < n) {
        float4 f = *(const float4*)(in + i);
        ushort4 o;
        o.x = f32_to_bf16_rne(f.x); o.y = f32_to_bf16_rne(f.y);
        o.z = f32_to_bf16_rne(f.z); o.w = f32_to_bf16_rne(f.w);
        *(ushort4*)(out + i) = o;
    }
}

// ---------------- core 128x128 B^T GEMM tile (m93 structure) ----------------
// C[m0+0..127][n0+0..127] = alpha * sum_k A[m][k]*Bt[n][k] (+ bias[n])
// A row-major [*,lda] bf16; Bt row-major [*,ldb] bf16. K multiple of 32.
// 256 threads = 4 waves in 2x2, each wave 64x64 via 4x4 mfma_f32_16x16x32_bf16.
template<bool BF16_OUT, bool HAS_BIAS>
__device__ __forceinline__ void gemm_tile_128(
    const u16* __restrict__ A, int lda,
    const u16* __restrict__ Bt, int ldb,
    void* __restrict__ Cout, int ldc,
    const float* __restrict__ bias,
    int m0, int n0, int K, float alpha)
{
    __shared__ u16 la[128 * 32];
    __shared__ u16 lb[128 * 32];

    const int tid  = threadIdx.x;
    const int lane = tid & 63;
    const int wave = tid >> 6;
    const int wm = (wave & 1) * 64;   // wave m-offset in tile
    const int wn = (wave >> 1) * 64;  // wave n-offset in tile

    // staging: 128x32 bf16 tile = 512 x short8 chunks; each thread does 2 for A, 2 for B
    const int r0 = tid >> 2;            // 0..63
    const int c0 = (tid & 3) * 8;       // 0,8,16,24

    f32x4 acc[4][4];
#pragma unroll
    for (int mt = 0; mt < 4; mt++)
#pragma unroll
        for (int nt = 0; nt < 4; nt++)
            acc[mt][nt] = f32x4{0.f, 0.f, 0.f, 0.f};

    const int mrow = wm + (lane & 15);
    const int nrow = wn + (lane & 15);
    const int koff = (lane >> 4) * 8;

    for (int kk = 0; kk < K; kk += 32) {
        bf16x8 a0 = *(const bf16x8*)(A  + (size_t)(m0 + r0)      * lda + kk + c0);
        bf16x8 a1 = *(const bf16x8*)(A  + (size_t)(m0 + r0 + 64) * lda + kk + c0);
        bf16x8 b0 = *(const bf16x8*)(Bt + (size_t)(n0 + r0)      * ldb + kk + c0);
        bf16x8 b1 = *(const bf16x8*)(Bt + (size_t)(n0 + r0 + 64) * ldb + kk + c0);
        __syncthreads();   // previous iteration's LDS reads complete
        *(bf16x8*)(la + r0 * 32 + c0)        = a0;
        *(bf16x8*)(la + (r0 + 64) * 32 + c0) = a1;
        *(bf16x8*)(lb + r0 * 32 + c0)        = b0;
        *(bf16x8*)(lb + (r0 + 64) * 32 + c0) = b1;
        __syncthreads();

        bf16x8 fa[4], fb[4];
#pragma unroll
        for (int t = 0; t < 4; t++) {
            fa[t] = *(const bf16x8*)(la + (mrow + t * 16) * 32 + koff);
            fb[t] = *(const bf16x8*)(lb + (nrow + t * 16) * 32 + koff);
        }
#pragma unroll
        for (int mt = 0; mt < 4; mt++)
#pragma unroll
            for (int nt = 0; nt < 4; nt++)
                acc[mt][nt] = __builtin_amdgcn_mfma_f32_16x16x32_bf16(
                    fa[mt], fb[nt], acc[mt][nt], 0, 0, 0);
    }

    // epilogue: C/D layout col=lane&15, row=(lane>>4)*4+reg  [verified m89/m91]
    const int col   = lane & 15;
    const int rquad = (lane >> 4) * 4;
#pragma unroll
    for (int mt = 0; mt < 4; mt++) {
#pragma unroll
        for (int nt = 0; nt < 4; nt++) {
            const int n = n0 + wn + nt * 16 + col;
            float badd = HAS_BIAS ? bias[n] : 0.0f;
#pragma unroll
            for (int r = 0; r < 4; r++) {
                const int m = m0 + wm + mt * 16 + rquad + r;
                float val = acc[mt][nt][r] * alpha + badd;
                if (BF16_OUT)
                    ((u16*)Cout)[(size_t)m * ldc + n] = f32_to_bf16_rne(val);
                else
                    ((float*)Cout)[(size_t)m * ldc + n] = val;
            }
        }
    }
}

// ---------------- QKV projection: qkv[which] = xb @ Wb[which]^T + b ----------------
__global__ __launch_bounds__(256) void k_qkv(const u16* __restrict__ xb,
                                             const u16* __restrict__ Wb,
                                             const float* __restrict__ bq,
                                             const float* __restrict__ bk,
                                             const float* __restrict__ bv,
                                             u16* __restrict__ qkv) {
    const int which = blockIdx.y;
    const int bx = blockIdx.x;            // 128 m-tiles x 8 n-tiles
    const int m0 = (bx >> 3) * 128;
    const int n0 = (bx & 7) * 128;
    const float* bias = (which == 0) ? bq : (which == 1) ? bk : bv;
    gemm_tile_128<true, true>(xb, F_DIM,
                              Wb + (size_t)which * F_DIM * F_DIM, F_DIM,
                              qkv + (size_t)which * BS_TOT * F_DIM, F_DIM,
                              bias, m0, n0, F_DIM, 1.0f);
}

// ---------------- V transpose: v[S][F] -> vT[F][S] per batch ----------------
__global__ __launch_bounds__(256) void k_transpose(const u16* __restrict__ v,
                                                   u16* __restrict__ vT) {
    __shared__ u16 t[32][33];
    const int b = blockIdx.y;
    const int tileS = blockIdx.x >> 5;    // 0..63
    const int tileF = blockIdx.x & 31;    // 0..31
    const u16* vb = v + (size_t)b * S_LEN * F_DIM;
    u16* vTb = vT + (size_t)b * F_DIM * S_LEN;
    const int tx = threadIdx.x & 31, ty = threadIdx.x >> 5;  // ty 0..7
    const int s0 = tileS * 32, f0 = tileF * 32;
#pragma unroll
    for (int r = 0; r < 4; r++)
        t[ty + r * 8][tx] = vb[(size_t)(s0 + ty + r * 8) * F_DIM + f0 + tx];
    __syncthreads();
#pragma unroll
    for (int r = 0; r < 4; r++)
        vTb[(size_t)(f0 + ty + r * 8) * S_LEN + s0 + tx] = t[tx][ty + r * 8];
}

// ---------------- scores: lower-triangular tiles only ----------------
__global__ __launch_bounds__(256) void k_scores(const u16* __restrict__ q,
                                                const u16* __restrict__ k,
                                                float* __restrict__ scores) {
    const int b = blockIdx.y;
    const int t = blockIdx.x;            // 0..135 triangular index
    int it = 0, base = 0;
    while (base + it + 1 <= t) { base += it + 1; it++; }
    const int jt = t - base;
    gemm_tile_128<false, false>(q + (size_t)b * S_LEN * F_DIM, F_DIM,
                                k + (size_t)b * S_LEN * F_DIM, F_DIM,
                                scores + (size_t)b * S_LEN * S_LEN, S_LEN,
                                nullptr, it * 128, jt * 128, F_DIM, 0.03125f);
}

// ---------------- masked softmax row kernel -> P (bf16, zeros above diag) ----------------
__global__ __launch_bounds__(256) void k_softmax(const float* __restrict__ scores,
                                                 const int* __restrict__ pad,
                                                 u16* __restrict__ P) {
    const int b = blockIdx.y;
    const int i = blockIdx.x;
    const int tid = threadIdx.x;
    const float* srow = scores + ((size_t)b * S_LEN + i) * S_LEN;
    const int* prow = pad + (size_t)b * S_LEN;
    u16* orow = P + ((size_t)b * S_LEN + i) * S_LEN;

    float sv[8];
    bool vld[8];
    float m = -1e30f;
#pragma unroll
    for (int l = 0; l < 8; l++) {
        const int j = tid + l * 256;
        const bool ok = (j <= i) && (prow[j] != 0);
        const float s = ok ? srow[j] : -1e30f;
        vld[l] = ok; sv[l] = s;
        m = fmaxf(m, s);
    }
    for (int off = 32; off > 0; off >>= 1) m = fmaxf(m, __shfl_xor(m, off));
    __shared__ float wmax[4], wsum[4];
    const int lane = tid & 63, wv = tid >> 6;
    if (lane == 0) wmax[wv] = m;
    __syncthreads();
    m = fmaxf(fmaxf(wmax[0], wmax[1]), fmaxf(wmax[2], wmax[3]));

    float ev[8];
    float sum = 0.f;
#pragma unroll
    for (int l = 0; l < 8; l++) {
        const float e = vld[l] ? __expf(sv[l] - m) : 0.f;
        ev[l] = e; sum += e;
    }
    for (int off = 32; off > 0; off >>= 1) sum += __shfl_xor(sum, off);
    if (lane == 0) wsum[wv] = sum;
    __syncthreads();
    sum = wsum[0] + wsum[1] + wsum[2] + wsum[3];
    const float inv = 1.0f / sum;
#pragma unroll
    for (int l = 0; l < 8; l++)
        orow[tid + l * 256] = f32_to_bf16_rne(ev[l] * inv);
}

// ---------------- PV: out = P @ V, k-tiles clipped at the diagonal ----------------
__global__ __launch_bounds__(256) void k_pv(const u16* __restrict__ P,
                                            const u16* __restrict__ vT,
                                            float* __restrict__ out) {
    const int b = blockIdx.y;
    const int it = blockIdx.x >> 3;       // 0..15 row tile
    const int nt = blockIdx.x & 7;        // 0..7 feature tile
    const int Keff = (it + 1) * 128;      // P is zero for k-tiles above diagonal
    gemm_tile_128<false, false>(P + (size_t)b * S_LEN * S_LEN, S_LEN,
                                vT + (size_t)b * F_DIM * S_LEN, S_LEN,
                                out + (size_t)b * S_LEN * F_DIM, F_DIM,
                                nullptr, it * 128, nt * 128, Keff, 1.0f);
}

extern "C" void kernel_launch(void* const* d_in, const int* in_sizes, int n_in,
                              void* d_out, int out_size, void* d_ws, size_t ws_size,
                              hipStream_t stream) {
    const float* x  = (const float*)d_in[0];
    // d_in[1] = attn_mask (causal tril) — structure hard-coded
    const int* pad  = (const int*)d_in[2];
    const float* Wq = (const float*)d_in[3];
    const float* bq = (const float*)d_in[4];
    const float* Wk = (const float*)d_in[5];
    const float* bk = (const float*)d_in[6];
    const float* Wv = (const float*)d_in[7];
    const float* bv = (const float*)d_in[8];
    float* out = (float*)d_out;

    char* ws = (char*)d_ws;
    // layout (peak 256MB):
    //   [0,96M)    qkv bf16 [3][16384][1024]    (q,k dead after scores; overlapped by P)
    //   [96,128M)  vT  bf16 [8][1024][2048]
    //   [128,160M) xb  bf16                     (dead after QKV; overlapped by scores)
    //   [160,166M) Wb  bf16 [3][1024][1024]     (dead after QKV)
    //   [128,256M) scores fp32 [8][2048][2048]
    //   [0,64M)    P   bf16 [8][2048][2048]
    u16* qkv  = (u16*)(ws);
    u16* vT   = (u16*)(ws + 96ull * 1024 * 1024);
    u16* xb   = (u16*)(ws + 128ull * 1024 * 1024);
    u16* Wb   = (u16*)(ws + 160ull * 1024 * 1024);
    float* sc = (float*)(ws + 128ull * 1024 * 1024);
    u16* P    = (u16*)(ws);

    const int BSF = BS_TOT * F_DIM;      // 16,777,216
    const int FF = F_DIM * F_DIM;        // 1,048,576

    cvt_f32_bf16<<<BSF / 1024, 256, 0, stream>>>(x, xb, BSF);
    cvt_f32_bf16<<<FF / 1024, 256, 0, stream>>>(Wq, Wb, FF);
    cvt_f32_bf16<<<FF / 1024, 256, 0, stream>>>(Wk, Wb + FF, FF);
    cvt_f32_bf16<<<FF / 1024, 256, 0, stream>>>(Wv, Wb + 2 * FF, FF);

    k_qkv<<<dim3(1024, 3), 256, 0, stream>>>(xb, Wb, bq, bk, bv, qkv);

    k_transpose<<<dim3(2048, 8), 256, 0, stream>>>(qkv + 2ull * BS_TOT * F_DIM, vT);

    k_scores<<<dim3(136, 8), 256, 0, stream>>>(qkv, qkv + (size_t)BS_TOT * F_DIM, sc);

    k_softmax<<<dim3(2048, 8), 256, 0, stream>>>(sc, pad, P);

    k_pv<<<dim3(128, 8), 256, 0, stream>>>(P, vT, out);
}

// Round 2
// 488.897 us; speedup vs baseline: 1.0351x; 1.0351x over previous
//
#include <hip/hip_runtime.h>
#include <hip/hip_bf16.h>
#include <stdint.h>

// Problem: B=8, S=2048, F=1024 single-head causal self-attention.
// q = x@Wq^T+bq ; k,v likewise ; scores = (q k^T)/32, pad+causal mask, softmax ; out = P v
// R2: m97-style global_load_lds width-16 staging in the GEMM K-loop (m93->m97 = 1.69x).

#define S_LEN 2048
#define F_DIM 1024
#define NBATCH 8
#define BS_TOT (NBATCH * S_LEN)   // 16384 rows

typedef __attribute__((ext_vector_type(8))) short bf16x8;
typedef __attribute__((ext_vector_type(4))) float f32x4;
typedef unsigned short u16;

__device__ __forceinline__ u16 f32_to_bf16_rne(float f) {
    union { float f; uint32_t u; } v; v.f = f;
    uint32_t u = v.u;
    u += 0x7FFFu + ((u >> 16) & 1u);
    return (u16)(u >> 16);
}

// async global->LDS, 16B per lane per instruction (global_load_lds_dwordx4)
__device__ __forceinline__ void gload_lds16(const u16* g, u16* l) {
    __builtin_amdgcn_global_load_lds(
        (const __attribute__((address_space(1))) void*)g,
        (__attribute__((address_space(3))) void*)l,
        16, 0, 0);
}

// ---------------- fp32 -> bf16 convert (vectorized) ----------------
__global__ __launch_bounds__(256) void cvt_f32_bf16(const float* __restrict__ in,
                                                    u16* __restrict__ out, int n) {
    int i = (blockIdx.x * 256 + threadIdx.x) * 4;
    if (i + 3 < n) {
        float4 f = *(const float4*)(in + i);
        ushort4 o;
        o.x = f32_to_bf16_rne(f.x); o.y = f32_to_bf16_rne(f.y);
        o.z = f32_to_bf16_rne(f.z); o.w = f32_to_bf16_rne(f.w);
        *(ushort4*)(out + i) = o;
    }
}

// ---------------- core 128x128 B^T GEMM tile (m97 structure) ----------------
// C[m0+0..127][n0+0..127] = alpha * sum_k A[m][k]*Bt[n][k] (+ bias[n])
// A row-major [*,lda] bf16; Bt row-major [*,ldb] bf16. K multiple of 32.
// 256 threads = 4 waves in 2x2, each wave 64x64 via 4x4 mfma_f32_16x16x32_bf16.
// Staging via global_load_lds width=16: 128x32 tile = 512 chunks of 16B; wave w
// instruction j covers chunks [w*64 + j*256, +64), chunk c -> LDS elem offset 8c
// (= row-major (c>>2)*32 + (c&3)*8), lane i lands at base + 16i. [m97 verified]
template<bool BF16_OUT, bool HAS_BIAS>
__device__ __forceinline__ void gemm_tile_128(
    const u16* __restrict__ A, int lda,
    const u16* __restrict__ Bt, int ldb,
    void* __restrict__ Cout, int ldc,
    const float* __restrict__ bias,
    int m0, int n0, int K, float alpha)
{
    __shared__ u16 la[128 * 32];
    __shared__ u16 lb[128 * 32];

    const int tid  = threadIdx.x;
    const int lane = tid & 63;
    const int wave = tid >> 6;
    const int wm = (wave & 1) * 64;   // wave m-offset in tile
    const int wn = (wave >> 1) * 64;  // wave n-offset in tile

    f32x4 acc[4][4];
#pragma unroll
    for (int mt = 0; mt < 4; mt++)
#pragma unroll
        for (int nt = 0; nt < 4; nt++)
            acc[mt][nt] = f32x4{0.f, 0.f, 0.f, 0.f};

    const int mrow = wm + (lane & 15);
    const int nrow = wn + (lane & 15);
    const int koff = (lane >> 4) * 8;

    // staging pointers: chunk bases cb0 = wave*64, cb1 = wave*64 + 256
    const int cb0 = wave * 64;
    const int cb1 = wave * 64 + 256;
    const int lrow = lane >> 2;          // row offset within instruction (0..15)
    const int lcol = (lane & 3) * 8;     // col offset (0,8,16,24)
    const u16* pa0 = A  + (size_t)(m0 + (cb0 >> 2) + lrow) * lda + lcol;
    const u16* pa1 = A  + (size_t)(m0 + (cb1 >> 2) + lrow) * lda + lcol;
    const u16* pb0 = Bt + (size_t)(n0 + (cb0 >> 2) + lrow) * ldb + lcol;
    const u16* pb1 = Bt + (size_t)(n0 + (cb1 >> 2) + lrow) * ldb + lcol;
    u16* qa0 = la + cb0 * 8;   // wave-uniform LDS bases
    u16* qa1 = la + cb1 * 8;
    u16* qb0 = lb + cb0 * 8;
    u16* qb1 = lb + cb1 * 8;

    for (int kk = 0; kk < K; kk += 32) {
        __syncthreads();   // previous iteration's LDS reads complete
        gload_lds16(pa0 + kk, qa0);
        gload_lds16(pa1 + kk, qa1);
        gload_lds16(pb0 + kk, qb0);
        gload_lds16(pb1 + kk, qb1);
        __syncthreads();   // drains vmcnt -> LDS tile valid

        bf16x8 fa[4], fb[4];
#pragma unroll
        for (int t = 0; t < 4; t++) {
            fa[t] = *(const bf16x8*)(la + (mrow + t * 16) * 32 + koff);
            fb[t] = *(const bf16x8*)(lb + (nrow + t * 16) * 32 + koff);
        }
#pragma unroll
        for (int mt = 0; mt < 4; mt++)
#pragma unroll
            for (int nt = 0; nt < 4; nt++)
                acc[mt][nt] = __builtin_amdgcn_mfma_f32_16x16x32_bf16(
                    fa[mt], fb[nt], acc[mt][nt], 0, 0, 0);
    }

    // epilogue: C/D layout col=lane&15, row=(lane>>4)*4+reg  [verified m89/m91]
    const int col   = lane & 15;
    const int rquad = (lane >> 4) * 4;
#pragma unroll
    for (int mt = 0; mt < 4; mt++) {
#pragma unroll
        for (int nt = 0; nt < 4; nt++) {
            const int n = n0 + wn + nt * 16 + col;
            float badd = HAS_BIAS ? bias[n] : 0.0f;
#pragma unroll
            for (int r = 0; r < 4; r++) {
                const int m = m0 + wm + mt * 16 + rquad + r;
                float val = acc[mt][nt][r] * alpha + badd;
                if (BF16_OUT)
                    ((u16*)Cout)[(size_t)m * ldc + n] = f32_to_bf16_rne(val);
                else
                    ((float*)Cout)[(size_t)m * ldc + n] = val;
            }
        }
    }
}

// ---------------- QKV projection: qkv[which] = xb @ Wb[which]^T + b ----------------
__global__ __launch_bounds__(256) void k_qkv(const u16* __restrict__ xb,
                                             const u16* __restrict__ Wb,
                                             const float* __restrict__ bq,
                                             const float* __restrict__ bk,
                                             const float* __restrict__ bv,
                                             u16* __restrict__ qkv) {
    const int which = blockIdx.y;
    const int bx = blockIdx.x;            // 128 m-tiles x 8 n-tiles
    const int m0 = (bx >> 3) * 128;
    const int n0 = (bx & 7) * 128;
    const float* bias = (which == 0) ? bq : (which == 1) ? bk : bv;
    gemm_tile_128<true, true>(xb, F_DIM,
                              Wb + (size_t)which * F_DIM * F_DIM, F_DIM,
                              qkv + (size_t)which * BS_TOT * F_DIM, F_DIM,
                              bias, m0, n0, F_DIM, 1.0f);
}

// ---------------- V transpose: v[S][F] -> vT[F][S] per batch ----------------
__global__ __launch_bounds__(256) void k_transpose(const u16* __restrict__ v,
                                                   u16* __restrict__ vT) {
    __shared__ u16 t[32][33];
    const int b = blockIdx.y;
    const int tileS = blockIdx.x >> 5;    // 0..63
    const int tileF = blockIdx.x & 31;    // 0..31
    const u16* vb = v + (size_t)b * S_LEN * F_DIM;
    u16* vTb = vT + (size_t)b * F_DIM * S_LEN;
    const int tx = threadIdx.x & 31, ty = threadIdx.x >> 5;  // ty 0..7
    const int s0 = tileS * 32, f0 = tileF * 32;
#pragma unroll
    for (int r = 0; r < 4; r++)
        t[ty + r * 8][tx] = vb[(size_t)(s0 + ty + r * 8) * F_DIM + f0 + tx];
    __syncthreads();
#pragma unroll
    for (int r = 0; r < 4; r++)
        vTb[(size_t)(f0 + ty + r * 8) * S_LEN + s0 + tx] = t[tx][ty + r * 8];
}

// ---------------- scores: lower-triangular tiles only ----------------
__global__ __launch_bounds__(256) void k_scores(const u16* __restrict__ q,
                                                const u16* __restrict__ k,
                                                float* __restrict__ scores) {
    const int b = blockIdx.y;
    const int t = blockIdx.x;            // 0..135 triangular index
    int it = 0, base = 0;
    while (base + it + 1 <= t) { base += it + 1; it++; }
    const int jt = t - base;
    gemm_tile_128<false, false>(q + (size_t)b * S_LEN * F_DIM, F_DIM,
                                k + (size_t)b * S_LEN * F_DIM, F_DIM,
                                scores + (size_t)b * S_LEN * S_LEN, S_LEN,
                                nullptr, it * 128, jt * 128, F_DIM, 0.03125f);
}

// ---------------- masked softmax row kernel -> P (bf16, zeros above diag) ----------------
__global__ __launch_bounds__(256) void k_softmax(const float* __restrict__ scores,
                                                 const int* __restrict__ pad,
                                                 u16* __restrict__ P) {
    const int b = blockIdx.y;
    const int i = blockIdx.x;
    const int tid = threadIdx.x;
    const float* srow = scores + ((size_t)b * S_LEN + i) * S_LEN;
    const int* prow = pad + (size_t)b * S_LEN;
    u16* orow = P + ((size_t)b * S_LEN + i) * S_LEN;

    float sv[8];
    bool vld[8];
    float m = -1e30f;
#pragma unroll
    for (int l = 0; l < 8; l++) {
        const int j = tid + l * 256;
        const bool ok = (j <= i) && (prow[j] != 0);
        const float s = ok ? srow[j] : -1e30f;
        vld[l] = ok; sv[l] = s;
        m = fmaxf(m, s);
    }
    for (int off = 32; off > 0; off >>= 1) m = fmaxf(m, __shfl_xor(m, off));
    __shared__ float wmax[4], wsum[4];
    const int lane = tid & 63, wv = tid >> 6;
    if (lane == 0) wmax[wv] = m;
    __syncthreads();
    m = fmaxf(fmaxf(wmax[0], wmax[1]), fmaxf(wmax[2], wmax[3]));

    float ev[8];
    float sum = 0.f;
#pragma unroll
    for (int l = 0; l < 8; l++) {
        const float e = vld[l] ? __expf(sv[l] - m) : 0.f;
        ev[l] = e; sum += e;
    }
    for (int off = 32; off > 0; off >>= 1) sum += __shfl_xor(sum, off);
    if (lane == 0) wsum[wv] = sum;
    __syncthreads();
    sum = wsum[0] + wsum[1] + wsum[2] + wsum[3];
    const float inv = 1.0f / sum;
#pragma unroll
    for (int l = 0; l < 8; l++)
        orow[tid + l * 256] = f32_to_bf16_rne(ev[l] * inv);
}

// ---------------- PV: out = P @ V, k-tiles clipped at the diagonal ----------------
__global__ __launch_bounds__(256) void k_pv(const u16* __restrict__ P,
                                            const u16* __restrict__ vT,
                                            float* __restrict__ out) {
    const int b = blockIdx.y;
    const int it = blockIdx.x >> 3;       // 0..15 row tile
    const int nt = blockIdx.x & 7;        // 0..7 feature tile
    const int Keff = (it + 1) * 128;      // P is zero for k-tiles above diagonal
    gemm_tile_128<false, false>(P + (size_t)b * S_LEN * S_LEN, S_LEN,
                                vT + (size_t)b * F_DIM * S_LEN, S_LEN,
                                out + (size_t)b * S_LEN * F_DIM, F_DIM,
                                nullptr, it * 128, nt * 128, Keff, 1.0f);
}

extern "C" void kernel_launch(void* const* d_in, const int* in_sizes, int n_in,
                              void* d_out, int out_size, void* d_ws, size_t ws_size,
                              hipStream_t stream) {
    const float* x  = (const float*)d_in[0];
    // d_in[1] = attn_mask (causal tril) — structure hard-coded
    const int* pad  = (const int*)d_in[2];
    const float* Wq = (const float*)d_in[3];
    const float* bq = (const float*)d_in[4];
    const float* Wk = (const float*)d_in[5];
    const float* bk = (const float*)d_in[6];
    const float* Wv = (const float*)d_in[7];
    const float* bv = (const float*)d_in[8];
    float* out = (float*)d_out;

    char* ws = (char*)d_ws;
    // layout (peak 256MB):
    //   [0,96M)    qkv bf16 [3][16384][1024]    (q,k dead after scores; overlapped by P)
    //   [96,128M)  vT  bf16 [8][1024][2048]
    //   [128,160M) xb  bf16                     (dead after QKV; overlapped by scores)
    //   [160,166M) Wb  bf16 [3][1024][1024]     (dead after QKV)
    //   [128,256M) scores fp32 [8][2048][2048]
    //   [0,64M)    P   bf16 [8][2048][2048]
    u16* qkv  = (u16*)(ws);
    u16* vT   = (u16*)(ws + 96ull * 1024 * 1024);
    u16* xb   = (u16*)(ws + 128ull * 1024 * 1024);
    u16* Wb   = (u16*)(ws + 160ull * 1024 * 1024);
    float* sc = (float*)(ws + 128ull * 1024 * 1024);
    u16* P    = (u16*)(ws);

    const int BSF = BS_TOT * F_DIM;      // 16,777,216
    const int FF = F_DIM * F_DIM;        // 1,048,576

    cvt_f32_bf16<<<BSF / 1024, 256, 0, stream>>>(x, xb, BSF);
    cvt_f32_bf16<<<FF / 1024, 256, 0, stream>>>(Wq, Wb, FF);
    cvt_f32_bf16<<<FF / 1024, 256, 0, stream>>>(Wk, Wb + FF, FF);
    cvt_f32_bf16<<<FF / 1024, 256, 0, stream>>>(Wv, Wb + 2 * FF, FF);

    k_qkv<<<dim3(1024, 3), 256, 0, stream>>>(xb, Wb, bq, bk, bv, qkv);

    k_transpose<<<dim3(2048, 8), 256, 0, stream>>>(qkv + 2ull * BS_TOT * F_DIM, vT);

    k_scores<<<dim3(136, 8), 256, 0, stream>>>(qkv, qkv + (size_t)BS_TOT * F_DIM, sc);

    k_softmax<<<dim3(2048, 8), 256, 0, stream>>>(sc, pad, P);

    k_pv<<<dim3(128, 8), 256, 0, stream>>>(P, vT, out);
}

// Round 3
// 428.501 us; speedup vs baseline: 1.1810x; 1.1409x over previous
//
#include <hip/hip_runtime.h>
#include <hip/hip_bf16.h>
#include <stdint.h>

// Problem: B=8, S=2048, F=1024 single-head causal self-attention.
// q = x@Wq^T+bq ; k,v likewise ; scores = (q k^T)/32, pad+causal mask, softmax ; out = P v
// R3: XCD-aware grid swizzle (kill 400MB cross-XCD A-tile re-fetch), bf16 scores,
//     triangular-clipped softmax I/O.

#define S_LEN 2048
#define F_DIM 1024
#define NBATCH 8
#define BS_TOT (NBATCH * S_LEN)   // 16384 rows

typedef __attribute__((ext_vector_type(8))) short bf16x8;
typedef __attribute__((ext_vector_type(4))) float f32x4;
typedef unsigned short u16;

__device__ __forceinline__ u16 f32_to_bf16_rne(float f) {
    union { float f; uint32_t u; } v; v.f = f;
    uint32_t u = v.u;
    u += 0x7FFFu + ((u >> 16) & 1u);
    return (u16)(u >> 16);
}
__device__ __forceinline__ float bf16_to_f32(u16 h) {
    union { uint32_t u; float f; } v; v.u = ((uint32_t)h) << 16;
    return v.f;
}

// async global->LDS, 16B per lane per instruction (global_load_lds_dwordx4)
__device__ __forceinline__ void gload_lds16(const u16* g, u16* l) {
    __builtin_amdgcn_global_load_lds(
        (const __attribute__((address_space(1))) void*)g,
        (__attribute__((address_space(3))) void*)l,
        16, 0, 0);
}

// ---------------- fp32 -> bf16 convert (vectorized) ----------------
__global__ __launch_bounds__(256) void cvt_f32_bf16(const float* __restrict__ in,
                                                    u16* __restrict__ out, int n) {
    int i = (blockIdx.x * 256 + threadIdx.x) * 4;
    if (i + 3 < n) {
        float4 f = *(const float4*)(in + i);
        ushort4 o;
        o.x = f32_to_bf16_rne(f.x); o.y = f32_to_bf16_rne(f.y);
        o.z = f32_to_bf16_rne(f.z); o.w = f32_to_bf16_rne(f.w);
        *(ushort4*)(out + i) = o;
    }
}

// ---------------- core 128x128 B^T GEMM tile (m97 structure) ----------------
// C[m0..+127][n0..+127] = alpha * sum_k A[m][k]*Bt[n][k] (+ bias[n])
// 256 threads = 4 waves in 2x2, each wave 64x64 via 4x4 mfma_f32_16x16x32_bf16.
// Staging: global_load_lds width=16 (wave-uniform LDS base + lane*16B). [m97]
template<bool BF16_OUT, bool HAS_BIAS>
__device__ __forceinline__ void gemm_tile_128(
    const u16* __restrict__ A, int lda,
    const u16* __restrict__ Bt, int ldb,
    void* __restrict__ Cout, int ldc,
    const float* __restrict__ bias,
    int m0, int n0, int K, float alpha)
{
    __shared__ u16 la[128 * 32];
    __shared__ u16 lb[128 * 32];

    const int tid  = threadIdx.x;
    const int lane = tid & 63;
    const int wave = tid >> 6;
    const int wm = (wave & 1) * 64;   // wave m-offset in tile
    const int wn = (wave >> 1) * 64;  // wave n-offset in tile

    f32x4 acc[4][4];
#pragma unroll
    for (int mt = 0; mt < 4; mt++)
#pragma unroll
        for (int nt = 0; nt < 4; nt++)
            acc[mt][nt] = f32x4{0.f, 0.f, 0.f, 0.f};

    const int mrow = wm + (lane & 15);
    const int nrow = wn + (lane & 15);
    const int koff = (lane >> 4) * 8;

    // staging: chunk bases cb0 = wave*64, cb1 = wave*64+256; chunk c -> row c>>2, col (c&3)*8
    const int cb0 = wave * 64;
    const int cb1 = wave * 64 + 256;
    const int lrow = lane >> 2;
    const int lcol = (lane & 3) * 8;
    const u16* pa0 = A  + (size_t)(m0 + (cb0 >> 2) + lrow) * lda + lcol;
    const u16* pa1 = A  + (size_t)(m0 + (cb1 >> 2) + lrow) * lda + lcol;
    const u16* pb0 = Bt + (size_t)(n0 + (cb0 >> 2) + lrow) * ldb + lcol;
    const u16* pb1 = Bt + (size_t)(n0 + (cb1 >> 2) + lrow) * ldb + lcol;
    u16* qa0 = la + cb0 * 8;
    u16* qa1 = la + cb1 * 8;
    u16* qb0 = lb + cb0 * 8;
    u16* qb1 = lb + cb1 * 8;

    for (int kk = 0; kk < K; kk += 32) {
        __syncthreads();
        gload_lds16(pa0 + kk, qa0);
        gload_lds16(pa1 + kk, qa1);
        gload_lds16(pb0 + kk, qb0);
        gload_lds16(pb1 + kk, qb1);
        __syncthreads();

        bf16x8 fa[4], fb[4];
#pragma unroll
        for (int t = 0; t < 4; t++) {
            fa[t] = *(const bf16x8*)(la + (mrow + t * 16) * 32 + koff);
            fb[t] = *(const bf16x8*)(lb + (nrow + t * 16) * 32 + koff);
        }
#pragma unroll
        for (int mt = 0; mt < 4; mt++)
#pragma unroll
            for (int nt = 0; nt < 4; nt++)
                acc[mt][nt] = __builtin_amdgcn_mfma_f32_16x16x32_bf16(
                    fa[mt], fb[nt], acc[mt][nt], 0, 0, 0);
    }

    // epilogue: C/D layout col=lane&15, row=(lane>>4)*4+reg  [verified m89/m91]
    const int col   = lane & 15;
    const int rquad = (lane >> 4) * 4;
#pragma unroll
    for (int mt = 0; mt < 4; mt++) {
#pragma unroll
        for (int nt = 0; nt < 4; nt++) {
            const int n = n0 + wn + nt * 16 + col;
            float badd = HAS_BIAS ? bias[n] : 0.0f;
#pragma unroll
            for (int r = 0; r < 4; r++) {
                const int m = m0 + wm + mt * 16 + rquad + r;
                float val = acc[mt][nt][r] * alpha + badd;
                if (BF16_OUT)
                    ((u16*)Cout)[(size_t)m * ldc + n] = f32_to_bf16_rne(val);
                else
                    ((float*)Cout)[(size_t)m * ldc + n] = val;
            }
        }
    }
}

// ---------------- QKV projection: qkv[which] = xb @ Wb[which]^T + b ----------------
// XCD swizzle: xcd = bx&7 owns m-tiles [16*xcd, 16*xcd+16) -> A fetched once per XCD.
__global__ __launch_bounds__(256) void k_qkv(const u16* __restrict__ xb,
                                             const u16* __restrict__ Wb,
                                             const float* __restrict__ bq,
                                             const float* __restrict__ bk,
                                             const float* __restrict__ bv,
                                             u16* __restrict__ qkv) {
    const int which = blockIdx.y;
    const int bx = blockIdx.x;
    const int xcd = bx & 7;
    const int idx = bx >> 3;              // 0..127
    const int m0 = (xcd * 16 + (idx >> 3)) * 128;
    const int n0 = (idx & 7) * 128;
    const float* bias = (which == 0) ? bq : (which == 1) ? bk : bv;
    gemm_tile_128<true, true>(xb, F_DIM,
                              Wb + (size_t)which * F_DIM * F_DIM, F_DIM,
                              qkv + (size_t)which * BS_TOT * F_DIM, F_DIM,
                              bias, m0, n0, F_DIM, 1.0f);
}

// ---------------- V transpose: v[S][F] -> vT[F][S] per batch ----------------
__global__ __launch_bounds__(256) void k_transpose(const u16* __restrict__ v,
                                                   u16* __restrict__ vT) {
    __shared__ u16 t[32][33];
    const int b = blockIdx.y;
    const int tileS = blockIdx.x >> 5;
    const int tileF = blockIdx.x & 31;
    const u16* vb = v + (size_t)b * S_LEN * F_DIM;
    u16* vTb = vT + (size_t)b * F_DIM * S_LEN;
    const int tx = threadIdx.x & 31, ty = threadIdx.x >> 5;
    const int s0 = tileS * 32, f0 = tileF * 32;
#pragma unroll
    for (int r = 0; r < 4; r++)
        t[ty + r * 8][tx] = vb[(size_t)(s0 + ty + r * 8) * F_DIM + f0 + tx];
    __syncthreads();
#pragma unroll
    for (int r = 0; r < 4; r++)
        vTb[(size_t)(f0 + ty + r * 8) * S_LEN + s0 + tx] = t[tx][ty + r * 8];
}

// ---------------- scores (bf16 out): lower-triangular tiles only ----------------
// 1D grid 1088; batch = bx&7 -> XCD = batch (q,k of one batch stay in one L2).
__global__ __launch_bounds__(256) void k_scores(const u16* __restrict__ q,
                                                const u16* __restrict__ k,
                                                u16* __restrict__ scores) {
    const int b = blockIdx.x & 7;
    const int t = blockIdx.x >> 3;        // 0..135 triangular index
    int it = 0, base = 0;
    while (base + it + 1 <= t) { base += it + 1; it++; }
    const int jt = t - base;
    gemm_tile_128<true, false>(q + (size_t)b * S_LEN * F_DIM, F_DIM,
                               k + (size_t)b * S_LEN * F_DIM, F_DIM,
                               scores + (size_t)b * S_LEN * S_LEN, S_LEN,
                               nullptr, it * 128, jt * 128, F_DIM, 0.03125f);
}

// ---------------- masked softmax (bf16 in) -> P (bf16), clipped at diag tile ----------
// 1D grid 16384; batch = bx&7 -> XCD = batch.
__global__ __launch_bounds__(256) void k_softmax(const u16* __restrict__ scores,
                                                 const int* __restrict__ pad,
                                                 u16* __restrict__ P) {
    const int b = blockIdx.x & 7;
    const int i = blockIdx.x >> 3;
    const int tid = threadIdx.x;
    const u16* srow = scores + ((size_t)b * S_LEN + i) * S_LEN;
    const int* prow = pad + (size_t)b * S_LEN;
    u16* orow = P + ((size_t)b * S_LEN + i) * S_LEN;
    const int jlim = ((i >> 7) + 1) << 7;   // = Keff of this row's tile in k_pv

    float sv[8];
    bool vld[8];
    float m = -1e30f;
#pragma unroll
    for (int l = 0; l < 8; l++) {
        const int j = tid + l * 256;
        const bool ok = (j <= i) && (j < jlim) && (prow[j] != 0);
        const float s = ok ? bf16_to_f32(srow[j]) : -1e30f;
        vld[l] = ok; sv[l] = s;
        m = fmaxf(m, s);
    }
    for (int off = 32; off > 0; off >>= 1) m = fmaxf(m, __shfl_xor(m, off));
    __shared__ float wmax[4], wsum[4];
    const int lane = tid & 63, wv = tid >> 6;
    if (lane == 0) wmax[wv] = m;
    __syncthreads();
    m = fmaxf(fmaxf(wmax[0], wmax[1]), fmaxf(wmax[2], wmax[3]));

    float ev[8];
    float sum = 0.f;
#pragma unroll
    for (int l = 0; l < 8; l++) {
        const float e = vld[l] ? __expf(sv[l] - m) : 0.f;
        ev[l] = e; sum += e;
    }
    for (int off = 32; off > 0; off >>= 1) sum += __shfl_xor(sum, off);
    if (lane == 0) wsum[wv] = sum;
    __syncthreads();
    sum = wsum[0] + wsum[1] + wsum[2] + wsum[3];
    const float inv = 1.0f / sum;
#pragma unroll
    for (int l = 0; l < 8; l++) {
        const int j = tid + l * 256;
        if (j < jlim)                     // k_pv never reads j >= jlim
            orow[j] = f32_to_bf16_rne(ev[l] * inv);
    }
}

// ---------------- PV: out = P @ V, k-tiles clipped at the diagonal ----------------
// 1D grid 1024; batch = bx&7 -> XCD = batch (P 8MB + vT 4MB per XCD).
__global__ __launch_bounds__(256) void k_pv(const u16* __restrict__ P,
                                            const u16* __restrict__ vT,
                                            float* __restrict__ out) {
    const int b = blockIdx.x & 7;
    const int rest = blockIdx.x >> 3;     // 0..127
    const int it = rest >> 3;             // 0..15 row tile
    const int nt = rest & 7;              // 0..7 feature tile
    const int Keff = (it + 1) * 128;      // P is zero/unwritten beyond this; never read
    gemm_tile_128<false, false>(P + (size_t)b * S_LEN * S_LEN, S_LEN,
                                vT + (size_t)b * F_DIM * S_LEN, S_LEN,
                                out + (size_t)b * S_LEN * F_DIM, F_DIM,
                                nullptr, it * 128, nt * 128, Keff, 1.0f);
}

extern "C" void kernel_launch(void* const* d_in, const int* in_sizes, int n_in,
                              void* d_out, int out_size, void* d_ws, size_t ws_size,
                              hipStream_t stream) {
    const float* x  = (const float*)d_in[0];
    // d_in[1] = attn_mask (causal tril) — structure hard-coded
    const int* pad  = (const int*)d_in[2];
    const float* Wq = (const float*)d_in[3];
    const float* bq = (const float*)d_in[4];
    const float* Wk = (const float*)d_in[5];
    const float* bk = (const float*)d_in[6];
    const float* Wv = (const float*)d_in[7];
    const float* bv = (const float*)d_in[8];
    float* out = (float*)d_out;

    char* ws = (char*)d_ws;
    // layout:
    //   [0,96M)    qkv bf16 [3][16384][1024]   (q,k dead after scores; overlapped by P)
    //   [96,128M)  vT  bf16 [8][1024][2048]
    //   [128,160M) xb  bf16                    (dead after QKV; overlapped by sc)
    //   [160,166M) Wb  bf16 [3][1024][1024]    (dead after QKV; overlapped by sc)
    //   [128,192M) sc  bf16 [8][2048][2048]
    //   [0,64M)    P   bf16 [8][2048][2048]
    u16* qkv  = (u16*)(ws);
    u16* vT   = (u16*)(ws + 96ull * 1024 * 1024);
    u16* xb   = (u16*)(ws + 128ull * 1024 * 1024);
    u16* Wb   = (u16*)(ws + 160ull * 1024 * 1024);
    u16* sc   = (u16*)(ws + 128ull * 1024 * 1024);
    u16* P    = (u16*)(ws);

    const int BSF = BS_TOT * F_DIM;      // 16,777,216
    const int FF = F_DIM * F_DIM;        // 1,048,576

    cvt_f32_bf16<<<BSF / 1024, 256, 0, stream>>>(x, xb, BSF);
    cvt_f32_bf16<<<FF / 1024, 256, 0, stream>>>(Wq, Wb, FF);
    cvt_f32_bf16<<<FF / 1024, 256, 0, stream>>>(Wk, Wb + FF, FF);
    cvt_f32_bf16<<<FF / 1024, 256, 0, stream>>>(Wv, Wb + 2 * FF, FF);

    k_qkv<<<dim3(1024, 3), 256, 0, stream>>>(xb, Wb, bq, bk, bv, qkv);

    k_transpose<<<dim3(2048, 8), 256, 0, stream>>>(qkv + 2ull * BS_TOT * F_DIM, vT);

    k_scores<<<1088, 256, 0, stream>>>(qkv, qkv + (size_t)BS_TOT * F_DIM, sc);

    k_softmax<<<16384, 256, 0, stream>>>(sc, pad, P);

    k_pv<<<1024, 256, 0, stream>>>(P, vT, out);
}

// Round 4
// 408.040 us; speedup vs baseline: 1.2402x; 1.0501x over previous
//
#include <hip/hip_runtime.h>
#include <hip/hip_bf16.h>
#include <stdint.h>

// Problem: B=8, S=2048, F=1024 single-head causal self-attention.
// R4: softmax folded into scores epilogue via fixed-offset exp (P'=exp(s-16), safe:
// |s|<=|q||k|/32~32, bf16 exp range = fp32), per-row 1/l applied in PV epilogue.
// k_softmax and k_transpose kernels deleted (vT written by qkv epilogue).

#define S_LEN 2048
#define F_DIM 1024
#define NBATCH 8
#define BS_TOT (NBATCH * S_LEN)   // 16384 rows

typedef __attribute__((ext_vector_type(8))) short bf16x8;
typedef __attribute__((ext_vector_type(4))) float f32x4;
typedef unsigned short u16;

__device__ __forceinline__ u16 f32_to_bf16_rne(float f) {
    union { float f; uint32_t u; } v; v.f = f;
    uint32_t u = v.u;
    u += 0x7FFFu + ((u >> 16) & 1u);
    return (u16)(u >> 16);
}
__device__ __forceinline__ float bf16_to_f32(u16 h) {
    union { uint32_t u; float f; } v; v.u = ((uint32_t)h) << 16;
    return v.f;
}

// async global->LDS, 16B per lane per instruction (global_load_lds_dwordx4)
__device__ __forceinline__ void gload_lds16(const u16* g, u16* l) {
    __builtin_amdgcn_global_load_lds(
        (const __attribute__((address_space(1))) void*)g,
        (__attribute__((address_space(3))) void*)l,
        16, 0, 0);
}

// ---------------- fp32 -> bf16 converts ----------------
__global__ __launch_bounds__(256) void cvt_f32_bf16(const float* __restrict__ in,
                                                    u16* __restrict__ out, int n) {
    int i = (blockIdx.x * 256 + threadIdx.x) * 4;
    if (i + 3 < n) {
        float4 f = *(const float4*)(in + i);
        ushort4 o;
        o.x = f32_to_bf16_rne(f.x); o.y = f32_to_bf16_rne(f.y);
        o.z = f32_to_bf16_rne(f.z); o.w = f32_to_bf16_rne(f.w);
        *(ushort4*)(out + i) = o;
    }
}

__global__ __launch_bounds__(256) void cvt_w3(const float* __restrict__ Wq,
                                              const float* __restrict__ Wk,
                                              const float* __restrict__ Wv,
                                              u16* __restrict__ Wb) {
    const int which = blockIdx.y;
    const float* in = (which == 0) ? Wq : (which == 1) ? Wk : Wv;
    int i = (blockIdx.x * 256 + threadIdx.x) * 4;
    float4 f = *(const float4*)(in + i);
    ushort4 o;
    o.x = f32_to_bf16_rne(f.x); o.y = f32_to_bf16_rne(f.y);
    o.z = f32_to_bf16_rne(f.z); o.w = f32_to_bf16_rne(f.w);
    *(ushort4*)(Wb + (size_t)which * F_DIM * F_DIM + i) = o;
}

// ---------------- core 128x128 B^T GEMM tile (m97 structure) ----------------
// acc = alpha * sum_k A[m][k]*Bt[n][k]; epilogue via inlined functor epi(m,n,val).
// 256 threads = 4 waves in 2x2, each wave 64x64 via 4x4 mfma_f32_16x16x32_bf16.
// Staging: global_load_lds width=16 (wave-uniform LDS base + lane*16B). [m97]
template<class Epi>
__device__ __forceinline__ void gemm_tile_128(
    const u16* __restrict__ A, int lda,
    const u16* __restrict__ Bt, int ldb,
    int m0, int n0, int K, float alpha, Epi epi)
{
    __shared__ u16 la[128 * 32];
    __shared__ u16 lb[128 * 32];

    const int tid  = threadIdx.x;
    const int lane = tid & 63;
    const int wave = tid >> 6;
    const int wm = (wave & 1) * 64;
    const int wn = (wave >> 1) * 64;

    f32x4 acc[4][4];
#pragma unroll
    for (int mt = 0; mt < 4; mt++)
#pragma unroll
        for (int nt = 0; nt < 4; nt++)
            acc[mt][nt] = f32x4{0.f, 0.f, 0.f, 0.f};

    const int mrow = wm + (lane & 15);
    const int nrow = wn + (lane & 15);
    const int koff = (lane >> 4) * 8;

    const int cb0 = wave * 64;
    const int cb1 = wave * 64 + 256;
    const int lrow = lane >> 2;
    const int lcol = (lane & 3) * 8;
    const u16* pa0 = A  + (size_t)(m0 + (cb0 >> 2) + lrow) * lda + lcol;
    const u16* pa1 = A  + (size_t)(m0 + (cb1 >> 2) + lrow) * lda + lcol;
    const u16* pb0 = Bt + (size_t)(n0 + (cb0 >> 2) + lrow) * ldb + lcol;
    const u16* pb1 = Bt + (size_t)(n0 + (cb1 >> 2) + lrow) * ldb + lcol;
    u16* qa0 = la + cb0 * 8;
    u16* qa1 = la + cb1 * 8;
    u16* qb0 = lb + cb0 * 8;
    u16* qb1 = lb + cb1 * 8;

    for (int kk = 0; kk < K; kk += 32) {
        __syncthreads();
        gload_lds16(pa0 + kk, qa0);
        gload_lds16(pa1 + kk, qa1);
        gload_lds16(pb0 + kk, qb0);
        gload_lds16(pb1 + kk, qb1);
        __syncthreads();

        bf16x8 fa[4], fb[4];
#pragma unroll
        for (int t = 0; t < 4; t++) {
            fa[t] = *(const bf16x8*)(la + (mrow + t * 16) * 32 + koff);
            fb[t] = *(const bf16x8*)(lb + (nrow + t * 16) * 32 + koff);
        }
#pragma unroll
        for (int mt = 0; mt < 4; mt++)
#pragma unroll
            for (int nt = 0; nt < 4; nt++)
                acc[mt][nt] = __builtin_amdgcn_mfma_f32_16x16x32_bf16(
                    fa[mt], fb[nt], acc[mt][nt], 0, 0, 0);
    }

    // C/D layout col=lane&15, row=(lane>>4)*4+reg  [verified m89/m91]
    const int col   = lane & 15;
    const int rquad = (lane >> 4) * 4;
#pragma unroll
    for (int mt = 0; mt < 4; mt++)
#pragma unroll
        for (int nt = 0; nt < 4; nt++) {
            const int n = n0 + wn + nt * 16 + col;
#pragma unroll
            for (int r = 0; r < 4; r++) {
                const int m = m0 + wm + mt * 16 + rquad + r;
                epi(m, n, acc[mt][nt][r] * alpha);
            }
        }
}

// ---------------- QKV projection ----------------
// which 0/1 -> q/k row-major; which 2 -> vT[b][f][s] written transposed.
// XCD swizzle: xcd = bx&7 owns m-tiles [16*xcd,16*xcd+16) -> A fetched once per XCD.
__global__ __launch_bounds__(256) void k_qkv(const u16* __restrict__ xb,
                                             const u16* __restrict__ Wb,
                                             const float* __restrict__ bq,
                                             const float* __restrict__ bk,
                                             const float* __restrict__ bv,
                                             u16* __restrict__ q,
                                             u16* __restrict__ k,
                                             u16* __restrict__ vT) {
    const int which = blockIdx.y;
    const int bx = blockIdx.x;
    const int xcd = bx & 7;
    const int idx = bx >> 3;
    const int m0 = (xcd * 16 + (idx >> 3)) * 128;
    const int n0 = (idx & 7) * 128;
    const float* bias = (which == 0) ? bq : (which == 1) ? bk : bv;
    const u16* W = Wb + (size_t)which * F_DIM * F_DIM;
    if (which < 2) {
        u16* o = (which == 0) ? q : k;
        gemm_tile_128(xb, F_DIM, W, F_DIM, m0, n0, F_DIM, 1.0f,
            [&](int m, int n, float v) {
                o[(size_t)m * F_DIM + n] = f32_to_bf16_rne(v + bias[n]);
            });
    } else {
        gemm_tile_128(xb, F_DIM, W, F_DIM, m0, n0, F_DIM, 1.0f,
            [&](int m, int n, float v) {
                // vT[b][n][s], b = m>>11, s = m&2047
                vT[((size_t)(m >> 11) * F_DIM + n) * S_LEN + (m & 2047)] =
                    f32_to_bf16_rne(v + bias[n]);
            });
    }
}

// ---------------- scores -> P' = exp(s-16) masked, bf16, triangular tiles ----------
// 1D grid 1088; batch = bx&7 -> XCD = batch.
__global__ __launch_bounds__(256) void k_scores(const u16* __restrict__ q,
                                                const u16* __restrict__ k,
                                                const int* __restrict__ pad,
                                                u16* __restrict__ Pp) {
    const int b = blockIdx.x & 7;
    const int t = blockIdx.x >> 3;        // 0..135 triangular index
    int it = 0, base = 0;
    while (base + it + 1 <= t) { base += it + 1; it++; }
    const int jt = t - base;
    const int* padb = pad + b * S_LEN;
    u16* Pb = Pp + (size_t)b * S_LEN * S_LEN;
    gemm_tile_128(q + (size_t)b * S_LEN * F_DIM, F_DIM,
                  k + (size_t)b * S_LEN * F_DIM, F_DIM,
                  it * 128, jt * 128, F_DIM, 0.03125f,
        [&](int m, int n, float v) {
            u16 o = 0;
            if (n <= m && padb[n] != 0)
                o = f32_to_bf16_rne(__expf(v - 16.0f));
            Pb[(size_t)m * S_LEN + n] = o;
        });
}

// ---------------- row sums of P' -> inv_l (one wave per row, bf16x8 reads) --------
__global__ __launch_bounds__(256) void k_rowsum(const u16* __restrict__ Pp,
                                                float* __restrict__ invl) {
    const int wave = threadIdx.x >> 6, lane = threadIdx.x & 63;
    const int r = blockIdx.x * 4 + wave;      // 0..16383
    const int b = r >> 11, i = r & 2047;
    const int jlim = ((i >> 7) + 1) << 7;     // valid row extent (tile-rounded)
    const u16* row = Pp + (size_t)b * S_LEN * S_LEN + (size_t)i * S_LEN;
    float s = 0.f;
    for (int j0 = lane * 8; j0 < jlim; j0 += 512) {
        bf16x8 v = *(const bf16x8*)(row + j0);
#pragma unroll
        for (int e = 0; e < 8; e++) s += bf16_to_f32((u16)v[e]);
    }
    for (int off = 32; off > 0; off >>= 1) s += __shfl_xor(s, off);
    if (lane == 0) invl[r] = 1.0f / s;
}

// ---------------- PV: out = (P' @ V) * inv_l, k-tiles clipped at diagonal ---------
// 1D grid 1024; batch = bx&7 -> XCD = batch.
__global__ __launch_bounds__(256) void k_pv(const u16* __restrict__ Pp,
                                            const u16* __restrict__ vT,
                                            const float* __restrict__ invl,
                                            float* __restrict__ out) {
    const int b = blockIdx.x & 7;
    const int rest = blockIdx.x >> 3;
    const int it = rest >> 3;
    const int nt = rest & 7;
    const int Keff = (it + 1) * 128;
    const float* il = invl + b * S_LEN;
    float* ob = out + (size_t)b * S_LEN * F_DIM;
    gemm_tile_128(Pp + (size_t)b * S_LEN * S_LEN, S_LEN,
                  vT + (size_t)b * F_DIM * S_LEN, S_LEN,
                  it * 128, nt * 128, Keff, 1.0f,
        [&](int m, int n, float v) {
            ob[(size_t)m * F_DIM + n] = v * il[m];
        });
}

extern "C" void kernel_launch(void* const* d_in, const int* in_sizes, int n_in,
                              void* d_out, int out_size, void* d_ws, size_t ws_size,
                              hipStream_t stream) {
    const float* x  = (const float*)d_in[0];
    // d_in[1] = attn_mask (causal tril) — structure hard-coded
    const int* pad  = (const int*)d_in[2];
    const float* Wq = (const float*)d_in[3];
    const float* bq = (const float*)d_in[4];
    const float* Wk = (const float*)d_in[5];
    const float* bk = (const float*)d_in[6];
    const float* Wv = (const float*)d_in[7];
    const float* bv = (const float*)d_in[8];
    float* out = (float*)d_out;

    char* ws = (char*)d_ws;
    // layout:
    //   [0,32M)    q    bf16 [8][2048][1024]
    //   [32,64M)   k    bf16 [8][2048][1024]
    //   [64,96M)   vT   bf16 [8][1024][2048]
    //   [96,160M)  P'   bf16 [8][2048][2048]  (= masked exp(s-16); triangular written)
    //   [160,192M) xb   bf16 [16384][1024]
    //   [192,198M) Wb   bf16 [3][1024][1024]
    //   [200,200M+64K) invl f32 [16384]
    u16* q    = (u16*)(ws);
    u16* k    = (u16*)(ws + 32ull * 1024 * 1024);
    u16* vT   = (u16*)(ws + 64ull * 1024 * 1024);
    u16* Pp   = (u16*)(ws + 96ull * 1024 * 1024);
    u16* xb   = (u16*)(ws + 160ull * 1024 * 1024);
    u16* Wb   = (u16*)(ws + 192ull * 1024 * 1024);
    float* il = (float*)(ws + 200ull * 1024 * 1024);

    const int BSF = BS_TOT * F_DIM;      // 16,777,216
    const int FF = F_DIM * F_DIM;        // 1,048,576

    cvt_f32_bf16<<<BSF / 1024, 256, 0, stream>>>(x, xb, BSF);
    cvt_w3<<<dim3(FF / 1024, 3), 256, 0, stream>>>(Wq, Wk, Wv, Wb);

    k_qkv<<<dim3(1024, 3), 256, 0, stream>>>(xb, Wb, bq, bk, bv, q, k, vT);

    k_scores<<<1088, 256, 0, stream>>>(q, k, pad, Pp);

    k_rowsum<<<4096, 256, 0, stream>>>(Pp, il);

    k_pv<<<1024, 256, 0, stream>>>(Pp, vT, il, out);
}